// Round 8
// baseline (335.551 us; speedup 1.0000x reference)
//
#include <hip/hip_runtime.h>

#define NTOK 8192
#define NH 16
#define DD 64
#define NEGF -1e30f
#define LOG2E 1.4426950408889634f

typedef __attribute__((ext_vector_type(8))) short bf16x8;
typedef __attribute__((ext_vector_type(4))) float f32x4;

#define MFMA(a, b, c) __builtin_amdgcn_mfma_f32_16x16x32_bf16((a), (b), (c), 0, 0, 0)
#define EXP2(x) __builtin_amdgcn_exp2f(x)

static __device__ __forceinline__ unsigned short f2bf(float x) {
    union { float f; unsigned u; } c; c.f = x;
    unsigned r = (c.u + 0x7FFFu + ((c.u >> 16) & 1u)) >> 16;
    return (unsigned short)r;
}
static __device__ __forceinline__ float bf2f(unsigned short x) {
    union { unsigned u; float f; } c; c.u = ((unsigned)x) << 16;
    return c.f;
}

// ---------------- fused q/k fp32 -> bf16 convert (q gets softmax scale) ----------------
__global__ __launch_bounds__(256) void cvt_qk(const float* __restrict__ q, const float* __restrict__ k,
                                              unsigned short* __restrict__ Qb, unsigned short* __restrict__ Kb,
                                              float qscale, int n8) {
    int t = blockIdx.x * blockDim.x + threadIdx.x;
    const float* s; unsigned short* d; float sc;
    if (t < n8) { s = q; d = Qb; sc = qscale; }
    else       { s = k; d = Kb; sc = 1.0f; t -= n8; }
    const float4* s4 = (const float4*)s;
    float4 a = s4[2 * (size_t)t], b = s4[2 * (size_t)t + 1];
    union { unsigned short u[8]; uint4 q4; } o;
    o.u[0] = f2bf(a.x * sc); o.u[1] = f2bf(a.y * sc);
    o.u[2] = f2bf(a.z * sc); o.u[3] = f2bf(a.w * sc);
    o.u[4] = f2bf(b.x * sc); o.u[5] = f2bf(b.y * sc);
    o.u[6] = f2bf(b.z * sc); o.u[7] = f2bf(b.w * sc);
    *(uint4*)(d + 8 * (size_t)t) = o.q4;
}

// ---------------- v (h,n,d) fp32 -> blocked vt[h][n>>5][d][n&31] bf16 ----------------
__global__ __launch_bounds__(256) void transpose_v(const float* __restrict__ v,
                                                   unsigned short* __restrict__ vt) {
    int h = blockIdx.x >> 7;
    int n0 = (blockIdx.x & 127) << 6;
    __shared__ unsigned short t[64][65];
    int tid = threadIdx.x;
    int col = tid & 63;      // d
    int rr = tid >> 6;       // 0..3
    const float* src = v + ((size_t)(h * NTOK + n0)) * DD;
#pragma unroll
    for (int r = 0; r < 16; ++r) {
        int row = rr + r * 4;   // n local
        t[col][row] = f2bf(src[(size_t)row * DD + col]);
    }
    __syncthreads();
    int d = tid >> 2, ch = tid & 3;
    union { unsigned short u[16]; uint4 q[2]; } tmp;
#pragma unroll
    for (int j = 0; j < 16; ++j) tmp.u[j] = t[d][ch * 16 + j];
    int b = (n0 >> 5) + (ch >> 1);
    unsigned short* dst = vt + ((size_t)(h * 256 + b)) * 2048 + d * 32 + (ch & 1) * 16;
    ((uint4*)dst)[0] = tmp.q[0];
    ((uint4*)dst)[1] = tmp.q[1];
}

// ---------------- level-1 pool: K1/V1 row-major + Vt1 blocked ----------------
__global__ __launch_bounds__(256) void pool1_kernel(const float* __restrict__ k, const float* __restrict__ v,
                                                    unsigned short* __restrict__ k1,
                                                    unsigned short* __restrict__ v1r,
                                                    unsigned short* __restrict__ vt1) {
    int tid = blockIdx.x * blockDim.x + threadIdx.x;   // NH*1024*64
    int d = tid & 63;
    int c = (tid >> 6) & 1023;
    int h = tid >> 16;
    size_t base = ((size_t)(h * NTOK + c * 8)) * DD + d;
    float ks = 0.f, vs = 0.f;
#pragma unroll
    for (int r = 0; r < 8; ++r) {
        ks += k[base + (size_t)r * DD];
        vs += v[base + (size_t)r * DD];
    }
    ks *= 0.125f; vs *= 0.125f;
    k1[((size_t)(h * 1024 + c)) * DD + d] = f2bf(ks);
    v1r[((size_t)(h * 1024 + c)) * DD + d] = f2bf(vs);
    vt1[((size_t)(h * 32 + (c >> 5))) * 2048 + d * 32 + (c & 31)] = f2bf(vs);
}

// ---------------- level-2 pool ----------------
__global__ __launch_bounds__(256) void pool2_kernel(const unsigned short* __restrict__ k1,
                                                    const unsigned short* __restrict__ v1r,
                                                    unsigned short* __restrict__ k2,
                                                    unsigned short* __restrict__ v2r,
                                                    unsigned short* __restrict__ vt2) {
    int tid = blockIdx.x * blockDim.x + threadIdx.x;   // NH*128*64
    int d = tid & 63;
    int c = (tid >> 6) & 127;
    int h = tid >> 13;
    float ks = 0.f, vs = 0.f;
#pragma unroll
    for (int j = 0; j < 8; ++j) {
        ks += bf2f(k1[((size_t)(h * 1024 + c * 8 + j)) * DD + d]);
        vs += bf2f(v1r[((size_t)(h * 1024 + c * 8 + j)) * DD + d]);
    }
    ks *= 0.125f; vs *= 0.125f;
    k2[((size_t)(h * 128 + c)) * DD + d] = f2bf(ks);
    v2r[((size_t)(h * 128 + c)) * DD + d] = f2bf(vs);
    vt2[((size_t)(h * 4 + (c >> 5))) * 2048 + d * 32 + (c & 31)] = f2bf(vs);
}

// ---------------- level-3 pool (16 real chunks, padded to 32) ----------------
__global__ __launch_bounds__(256) void pool3_kernel(const unsigned short* __restrict__ k2,
                                                    const unsigned short* __restrict__ v2r,
                                                    unsigned short* __restrict__ k3,
                                                    unsigned short* __restrict__ vt3) {
    int tid = blockIdx.x * blockDim.x + threadIdx.x;   // NH*32*64
    int d = tid & 63;
    int c = (tid >> 6) & 31;
    int h = tid >> 11;
    float ks = 0.f, vs = 0.f;
    if (c < 16) {
#pragma unroll
        for (int j = 0; j < 8; ++j) {
            ks += bf2f(k2[((size_t)(h * 128 + c * 8 + j)) * DD + d]);
            vs += bf2f(v2r[((size_t)(h * DD) * 2) * 0 + ((size_t)(h * 128 + c * 8 + j)) * DD + d]);
        }
        ks *= 0.125f; vs *= 0.125f;
    }
    k3[((size_t)(h * 32 + c)) * DD + d] = f2bf(ks);
    vt3[(size_t)h * 2048 + d * 32 + c] = f2bf(vs);
}

// ---------------- per-group compute: 32 queries (2 tiles) x 32 keys from LDS ----------------
// LDS layout (read-order): K tile 4KB @ kvbase: ka0@0 kb0@1024 ka1@2048 kb1@3072, lane slot
// +lane*16. V tile 4KB @ kvbase+4096: vf_db @ db*1024 + lane*16. All ds accesses conflict-free.
template<bool L0T>
__device__ __forceinline__ void compute_group(
    int c0, int Qs, int lgS, float gp, float gps,
    const char* kvbase, int lane_off, int g, int c,
    bf16x8 qa0, bf16x8 qa1, bf16x8 qb0, bf16x8 qb1,
    float& m, float& lA, float& lB, f32x4* oA, f32x4* oB)
{
    const bf16x8* kp = (const bf16x8*)(kvbase + lane_off);
    bf16x8 ka0 = kp[0], kb0 = kp[64], ka1 = kp[128], kb1 = kp[192];
    const bf16x8* vp = (const bf16x8*)(kvbase + 4096 + lane_off);
    bf16x8 vf0 = vp[0], vf1 = vp[64], vf2 = vp[128], vf3 = vp[192];

    const int i_qA = Qs + c, i_qB = i_qA + 16;

    f32x4 z = {0.f, 0.f, 0.f, 0.f};
    f32x4 sAA = MFMA(ka1, qa1, MFMA(ka0, qa0, z));
    f32x4 sAB = MFMA(kb1, qa1, MFMA(kb0, qa0, z));
    f32x4 sBA = MFMA(ka1, qb1, MFMA(ka0, qb0, z));
    f32x4 sBB = MFMA(kb1, qb1, MFMA(kb0, qb0, z));

    const float negfbA = gps * (float)(8 * g) + gp * (float)((1 << lgS) - 1) - gp * (float)i_qA;
    const float negfbB = negfbA - 16.f * gp;
    float c0f = (float)c0;

    float svA[8], svB[8];
    bool fastA, fastB;
    if (L0T) {
        fastA = (c0 >= Qs - 112) && (c0 + 31 <= Qs);
        fastB = (c0 >= Qs - 96) && (c0 + 31 <= Qs + 16);
    } else {
        int numA = Qs - 128 - ((1 << lgS) - 1);
        int numB = numA + 16;
        fastA = (numA >= 0) && (c0 + 31 <= (numA >> lgS));
        fastB = (numB >= 0) && (c0 + 31 <= (numB >> lgS));
    }
    if (fastA) {
        float u0 = fmaf(gps, c0f, negfbA);
        svA[0] = sAA[0] + u0;
        svA[1] = sAA[1] + fmaf(gps, 1.f, u0);
        svA[2] = sAA[2] + fmaf(gps, 2.f, u0);
        svA[3] = sAA[3] + fmaf(gps, 3.f, u0);
        svA[4] = sAB[0] + fmaf(gps, 4.f, u0);
        svA[5] = sAB[1] + fmaf(gps, 5.f, u0);
        svA[6] = sAB[2] + fmaf(gps, 6.f, u0);
        svA[7] = sAB[3] + fmaf(gps, 7.f, u0);
    } else {
#pragma unroll
        for (int r = 0; r < 4; ++r) {
            int cA = c0 + 8 * g + r, cB = cA + 4;
            int jA = L0T ? cA : (((cA + 1) << lgS) - 1);
            int jB = L0T ? cB : (((cB + 1) << lgS) - 1);
            int dA = i_qA - jA, dB = i_qA - jB;
            bool aA = L0T ? ((unsigned)dA <= 127u) : (dA >= 128);
            bool aB = L0T ? ((unsigned)dB <= 127u) : (dB >= 128);
            svA[r]     = aA ? fmaf(-gp, (float)dA, sAA[r]) : NEGF;
            svA[r + 4] = aB ? fmaf(-gp, (float)dB, sAB[r]) : NEGF;
        }
    }
    if (fastB) {
        float u0 = fmaf(gps, c0f, negfbB);
        svB[0] = sBA[0] + u0;
        svB[1] = sBA[1] + fmaf(gps, 1.f, u0);
        svB[2] = sBA[2] + fmaf(gps, 2.f, u0);
        svB[3] = sBA[3] + fmaf(gps, 3.f, u0);
        svB[4] = sBB[0] + fmaf(gps, 4.f, u0);
        svB[5] = sBB[1] + fmaf(gps, 5.f, u0);
        svB[6] = sBB[2] + fmaf(gps, 6.f, u0);
        svB[7] = sBB[3] + fmaf(gps, 7.f, u0);
    } else {
#pragma unroll
        for (int r = 0; r < 4; ++r) {
            int cA = c0 + 8 * g + r, cB = cA + 4;
            int jA = L0T ? cA : (((cA + 1) << lgS) - 1);
            int jB = L0T ? cB : (((cB + 1) << lgS) - 1);
            int dA = i_qB - jA, dB = i_qB - jB;
            bool aA = L0T ? ((unsigned)dA <= 127u) : (dA >= 128);
            bool aB = L0T ? ((unsigned)dB <= 127u) : (dB >= 128);
            svB[r]     = aA ? fmaf(-gp, (float)dA, sBA[r]) : NEGF;
            svB[r + 4] = aB ? fmaf(-gp, (float)dB, sBB[r]) : NEGF;
        }
    }

    // wave-uniform deferred max (no cross-lane reduce in steady state)
    float tm = fmaxf(
        fmaxf(fmaxf(fmaxf(svA[0], svA[1]), fmaxf(svA[2], svA[3])),
              fmaxf(fmaxf(svA[4], svA[5]), fmaxf(svA[6], svA[7]))),
        fmaxf(fmaxf(fmaxf(svB[0], svB[1]), fmaxf(svB[2], svB[3])),
              fmaxf(fmaxf(svB[4], svB[5]), fmaxf(svB[6], svB[7]))));
    if (__any(tm > m + 8.f)) {          // rare: newest-first => scores decay
        float wm = tm;
        wm = fmaxf(wm, __shfl_xor(wm, 1));
        wm = fmaxf(wm, __shfl_xor(wm, 2));
        wm = fmaxf(wm, __shfl_xor(wm, 4));
        wm = fmaxf(wm, __shfl_xor(wm, 8));
        wm = fmaxf(wm, __shfl_xor(wm, 16));
        wm = fmaxf(wm, __shfl_xor(wm, 32));
        float mn = fmaxf(m, wm);
        float sf = EXP2(m - mn);        // m=-1e30 -> 0
        m = mn;
        lA *= sf; lB *= sf;
        oA[0] *= sf; oA[1] *= sf; oA[2] *= sf; oA[3] *= sf;
        oB[0] *= sf; oB[1] *= sf; oB[2] *= sf; oB[3] *= sf;
    }

    // hardened base: if m is still NEG (all masked so far), exp2(sv - msafe) -> 0, not 1
    const float msafe = fmaxf(m, -1e20f);

    union { unsigned u32[4]; bf16x8 v8; } pfA, pfB;
    {
        float p[8];
#pragma unroll
        for (int r = 0; r < 8; ++r) p[r] = EXP2(svA[r] - msafe);
        lA += ((p[0] + p[1]) + (p[2] + p[3])) + ((p[4] + p[5]) + (p[6] + p[7]));
#pragma unroll
        for (int j = 0; j < 4; ++j)
            asm("v_cvt_pk_bf16_f32 %0, %1, %2" : "=v"(pfA.u32[j]) : "v"(p[2 * j]), "v"(p[2 * j + 1]));
    }
    {
        float p[8];
#pragma unroll
        for (int r = 0; r < 8; ++r) p[r] = EXP2(svB[r] - msafe);
        lB += ((p[0] + p[1]) + (p[2] + p[3])) + ((p[4] + p[5]) + (p[6] + p[7]));
#pragma unroll
        for (int j = 0; j < 4; ++j)
            asm("v_cvt_pk_bf16_f32 %0, %1, %2" : "=v"(pfB.u32[j]) : "v"(p[2 * j]), "v"(p[2 * j + 1]));
    }

    oA[0] = MFMA(vf0, pfA.v8, oA[0]);
    oB[0] = MFMA(vf0, pfB.v8, oB[0]);
    oA[1] = MFMA(vf1, pfA.v8, oA[1]);
    oB[1] = MFMA(vf1, pfB.v8, oB[1]);
    oA[2] = MFMA(vf2, pfA.v8, oA[2]);
    oB[2] = MFMA(vf2, pfB.v8, oB[2]);
    oA[3] = MFMA(vf3, pfA.v8, oA[3]);
    oB[3] = MFMA(vf3, pfB.v8, oB[3]);
}

// ---------------- main attention: 4 waves/block, 128 queries/block, reg->LDS staged K/V ----------------
__global__ __launch_bounds__(256, 4) void attn_mfma(
    const unsigned short* __restrict__ Qb, const unsigned short* __restrict__ Kb,
    const unsigned short* __restrict__ Vtb,
    const unsigned short* __restrict__ K1, const unsigned short* __restrict__ Vt1,
    const unsigned short* __restrict__ K2, const unsigned short* __restrict__ Vt2,
    const unsigned short* __restrict__ K3, const unsigned short* __restrict__ Vt3,
    const float* __restrict__ gam, float* __restrict__ out) {
    __shared__ __align__(1024) char smem[16384];   // 2 bufs x (K 4KB + V 4KB)

    const int tid = threadIdx.x;
    const int lane = tid & 63;
    const int wid = tid >> 6;
    const int h = blockIdx.x & 15;        // 2 heads per XCD (L2 locality)
    const int qblk = blockIdx.x >> 4;     // 0..63
    const int Qb128 = qblk << 7;          // block query base (128 queries)
    const int Qs = Qb128 + wid * 32;      // wave query base (32 queries)
    const int g = lane >> 4;
    const int c = lane & 15;
    const int lane_off = lane * 16;       // byte offset of this lane's LDS slot

    const float g0 = gam[0] * LOG2E, g1 = gam[1] * LOG2E;
    const float g2 = gam[2] * LOG2E, g3 = gam[3] * LOG2E;

    // head bases
    const unsigned short* KbH = Kb + (size_t)h * NTOK * DD;
    const unsigned short* VtH = Vtb + (size_t)h * 256 * 2048;
    const unsigned short* K1H = K1 + (size_t)h * 1024 * DD;
    const unsigned short* V1H = Vt1 + (size_t)h * 32 * 2048;
    const unsigned short* K2H = K2 + (size_t)h * 128 * DD;
    const unsigned short* V2H = Vt2 + (size_t)h * 4 * 2048;
    const unsigned short* K3H = K3 + (size_t)h * 32 * DD;
    const unsigned short* V3H = Vt3 + (size_t)h * 2048;

    // per-thread staging geometry: thread (wid,lane) owns LDS slot wid*1024 + lane*16
    // (K) and +4096 (V); it loads exactly the data that slot's reader expects.
    const int cc = lane & 15, gg = lane >> 4;
    const int key_st = 8 * (cc >> 2) + (cc & 3) + 4 * (wid & 1);   // K: tile = wid&1
    const int koff_st = (wid >> 1) * 32 + gg * 8;                  // K: dhalf = wid>>1
    const int voff_st = (cc + wid * 16) * 32 + gg * 8;             // V: db = wid
    const int stoff = wid * 1024 + lane_off;                       // LDS byte slot

    auto KSRC = [&](int L, int C) -> const uint4* {
        const unsigned short* Ks = (L == 0) ? KbH : (L == 1) ? K1H : (L == 2) ? K2H : K3H;
        return (const uint4*)(const void*)(Ks + (size_t)(C + key_st) * DD + koff_st);
    };
    auto VSRC = [&](int L, int C) -> const uint4* {
        const unsigned short* Vs = (L == 0) ? VtH : (L == 1) ? V1H : (L == 2) ? V2H : V3H;
        return (const uint4*)(const void*)(Vs + ((size_t)(C >> 5)) * 2048 + voff_st);
    };

    // block-uniform item list bounds
    int lo0 = Qb128 - 127; if (lo0 < 0) lo0 = 0; lo0 &= ~31;
    const int top0 = (Qb128 + 127) & ~31;
    const int top1 = (Qb128 - 8  >= 0) ? (((Qb128 - 8)  >> 3) & ~31) : -1;
    const int top2 = (Qb128 - 64 >= 0) ? (((Qb128 - 64) >> 6) & ~31) : -1;
    const bool has3 = (Qb128 >= 512);

    auto next_of = [&](int L, int C, int& nl, int& nc) {
        if (L == 0) {
            if (C - 32 >= lo0) { nl = 0; nc = C - 32; return; }
            if (top1 >= 0) { nl = 1; nc = top1; return; }
            if (top2 >= 0) { nl = 2; nc = top2; return; }
            if (has3) { nl = 3; nc = 0; return; }
            nl = -1; return;
        }
        if (L == 1) {
            if (C > 0) { nl = 1; nc = C - 32; return; }
            if (top2 >= 0) { nl = 2; nc = top2; return; }
            if (has3) { nl = 3; nc = 0; return; }
            nl = -1; return;
        }
        if (L == 2) {
            if (C > 0) { nl = 2; nc = C - 32; return; }
            if (has3) { nl = 3; nc = 0; return; }
            nl = -1; return;
        }
        nl = -1;
    };

    // Q fragments
    const unsigned short* QrowA = Qb + ((size_t)(h * NTOK + Qs + c)) * DD;
    bf16x8 qa0 = *(const bf16x8*)(const void*)(QrowA + g * 8);
    bf16x8 qa1 = *(const bf16x8*)(const void*)(QrowA + 32 + g * 8);
    const unsigned short* QrowB = QrowA + 16 * DD;
    bf16x8 qb0 = *(const bf16x8*)(const void*)(QrowB + g * 8);
    bf16x8 qb1 = *(const bf16x8*)(const void*)(QrowB + 32 + g * 8);

    f32x4 oA[4], oB[4];
#pragma unroll
    for (int t = 0; t < 4; ++t) { oA[t] = (f32x4){0.f,0.f,0.f,0.f}; oB[t] = (f32x4){0.f,0.f,0.f,0.f}; }
    float m = NEGF, lA = 0.f, lB = 0.f;

    int lvl = 0, c0 = top0, buf = 0;
    {   // prologue: stage first tile into buf0
        uint4 kr = *KSRC(lvl, c0);
        uint4 vr = *VSRC(lvl, c0);
        *(uint4*)(smem + stoff) = kr;
        *(uint4*)(smem + 4096 + stoff) = vr;
    }
    __syncthreads();

    for (;;) {
        int nlvl, nc0;
        next_of(lvl, c0, nlvl, nc0);
        uint4 kr = {0, 0, 0, 0}, vr = {0, 0, 0, 0};
        if (nlvl >= 0) {            // issue next tile's loads early (latency hides under compute)
            kr = *KSRC(nlvl, nc0);
            vr = *VSRC(nlvl, nc0);
        }

        // per-wave visibility skip (math only; barriers stay block-uniform)
        bool act;
        if (lvl == 0) act = (c0 <= Qs + 31) && (c0 + 31 >= Qs - 127);
        else {
            int lg = (lvl == 1) ? 3 : (lvl == 2) ? 6 : 9;
            int wn = Qs + 31 - 128 - ((1 << lg) - 1);
            act = (wn >= 0) && (c0 <= (wn >> lg));
        }
        if (act) {
            const char* kvb = smem + buf * 8192;
            switch (lvl) {
                case 0: compute_group<true >(c0, Qs, 0, g0, g0,          kvb, lane_off, g, c, qa0, qa1, qb0, qb1, m, lA, lB, oA, oB); break;
                case 1: compute_group<false>(c0, Qs, 3, g1, g1 * 8.f,    kvb, lane_off, g, c, qa0, qa1, qb0, qb1, m, lA, lB, oA, oB); break;
                case 2: compute_group<false>(c0, Qs, 6, g2, g2 * 64.f,   kvb, lane_off, g, c, qa0, qa1, qb0, qb1, m, lA, lB, oA, oB); break;
                default: compute_group<false>(c0, Qs, 9, g3, g3 * 512.f, kvb, lane_off, g, c, qa0, qa1, qb0, qb1, m, lA, lB, oA, oB); break;
            }
        }
        if (nlvl < 0) break;
        {   // write next tile into back buffer (waits vmcnt via data dep), then barrier
            char* dst = smem + (buf ^ 1) * 8192 + stoff;
            *(uint4*)dst = kr;
            *(uint4*)(dst + 4096) = vr;
        }
        __syncthreads();
        buf ^= 1; lvl = nlvl; c0 = nc0;
    }

    // final l reduce over the 4 g-lanes of each query column
    float ltA = lA + __shfl_xor(lA, 16); ltA += __shfl_xor(ltA, 32);
    float ltB = lB + __shfl_xor(lB, 16); ltB += __shfl_xor(ltB, 32);
    float invA = 1.0f / fmaxf(ltA, 1e-8f);
    float invB = 1.0f / fmaxf(ltB, 1e-8f);

    float* orowA = out + ((size_t)(h * NTOK + Qs + c)) * DD;
    float* orowB = orowA + 16 * DD;
#pragma unroll
    for (int db = 0; db < 4; ++db) {
        float4 x;
        x.x = oA[db][0] * invA; x.y = oA[db][1] * invA;
        x.z = oA[db][2] * invA; x.w = oA[db][3] * invA;
        *(float4*)(orowA + db * 16 + 4 * g) = x;
        float4 y;
        y.x = oB[db][0] * invB; y.y = oB[db][1] * invB;
        y.z = oB[db][2] * invB; y.w = oB[db][3] * invB;
        *(float4*)(orowB + db * 16 + 4 * g) = y;
    }
}

extern "C" void kernel_launch(void* const* d_in, const int* in_sizes, int n_in,
                              void* d_out, int out_size, void* d_ws, size_t ws_size,
                              hipStream_t stream) {
    const float* q = (const float*)d_in[0];
    const float* k = (const float*)d_in[1];
    const float* v = (const float*)d_in[2];
    const float* gam = (const float*)d_in[3];
    float* out = (float*)d_out;

    char* w = (char*)d_ws;
    const size_t bigN = (size_t)NH * NTOK * DD * sizeof(unsigned short);
    unsigned short* Qbuf = (unsigned short*)w;  w += bigN;
    unsigned short* Kbuf = (unsigned short*)w;  w += bigN;
    unsigned short* Vtb  = (unsigned short*)w;  w += bigN;                       // blocked
    unsigned short* K1   = (unsigned short*)w;  w += (size_t)NH * 1024 * DD * 2;
    unsigned short* V1r  = (unsigned short*)w;  w += (size_t)NH * 1024 * DD * 2;
    unsigned short* Vt1  = (unsigned short*)w;  w += (size_t)NH * 1024 * DD * 2; // blocked
    unsigned short* K2   = (unsigned short*)w;  w += (size_t)NH * 128 * DD * 2;
    unsigned short* V2r  = (unsigned short*)w;  w += (size_t)NH * 128 * DD * 2;
    unsigned short* Vt2  = (unsigned short*)w;  w += (size_t)NH * 128 * DD * 2;  // blocked
    unsigned short* K3   = (unsigned short*)w;  w += (size_t)NH * 32 * DD * 2;
    unsigned short* Vt3  = (unsigned short*)w;  w += (size_t)NH * 32 * DD * 2;   // blocked

    int n8 = NH * NTOK * DD / 8;
    const float qscale = 0.125f * LOG2E;   // fold softmax scale + log2e into Q
    cvt_qk<<<2 * n8 / 256, 256, 0, stream>>>(q, k, Qbuf, Kbuf, qscale, n8);
    transpose_v<<<NH * (NTOK / 64), 256, 0, stream>>>(v, Vtb);
    pool1_kernel<<<NH * 1024 * DD / 256, 256, 0, stream>>>(k, v, K1, V1r, Vt1);
    pool2_kernel<<<NH * 128 * DD / 256, 256, 0, stream>>>(K1, V1r, K2, V2r, Vt2);
    pool3_kernel<<<NH * 32 * DD / 256, 256, 0, stream>>>(K2, V2r, K3, Vt3);

    attn_mfma<<<NH * 64, 256, 0, stream>>>(Qbuf, Kbuf, Vtb, K1, Vt1, K2, Vt2, K3, Vt3, gam, out);
}

// Round 9
// 132.572 us; speedup vs baseline: 2.5311x; 2.5311x over previous
//
#include <hip/hip_runtime.h>

#define NTOK 8192
#define NH 16
#define DD 64
#define NEGF -1e30f
#define LOG2E 1.4426950408889634f

typedef __attribute__((ext_vector_type(8))) short bf16x8;
typedef __attribute__((ext_vector_type(4))) float f32x4;

#define MFMA(a, b, c) __builtin_amdgcn_mfma_f32_16x16x32_bf16((a), (b), (c), 0, 0, 0)
#define EXP2(x) __builtin_amdgcn_exp2f(x)

static __device__ __forceinline__ unsigned short f2bf(float x) {
    union { float f; unsigned u; } c; c.f = x;
    unsigned r = (c.u + 0x7FFFu + ((c.u >> 16) & 1u)) >> 16;
    return (unsigned short)r;
}
static __device__ __forceinline__ float bf2f(unsigned short x) {
    union { unsigned u; float f; } c; c.u = ((unsigned)x) << 16;
    return c.f;
}

// ---------------- fused q/k fp32 -> bf16 convert (q gets softmax scale) ----------------
__global__ __launch_bounds__(256) void cvt_qk(const float* __restrict__ q, const float* __restrict__ k,
                                              unsigned short* __restrict__ Qb, unsigned short* __restrict__ Kb,
                                              float qscale, int n8) {
    int t = blockIdx.x * blockDim.x + threadIdx.x;
    const float* s; unsigned short* d; float sc;
    if (t < n8) { s = q; d = Qb; sc = qscale; }
    else       { s = k; d = Kb; sc = 1.0f; t -= n8; }
    const float4* s4 = (const float4*)s;
    float4 a = s4[2 * (size_t)t], b = s4[2 * (size_t)t + 1];
    union { unsigned short u[8]; uint4 q4; } o;
    o.u[0] = f2bf(a.x * sc); o.u[1] = f2bf(a.y * sc);
    o.u[2] = f2bf(a.z * sc); o.u[3] = f2bf(a.w * sc);
    o.u[4] = f2bf(b.x * sc); o.u[5] = f2bf(b.y * sc);
    o.u[6] = f2bf(b.z * sc); o.u[7] = f2bf(b.w * sc);
    *(uint4*)(d + 8 * (size_t)t) = o.q4;
}

// ---------------- v (h,n,d) fp32 -> blocked vt[h][n>>5][d][n&31] bf16 ----------------
__global__ __launch_bounds__(256) void transpose_v(const float* __restrict__ v,
                                                   unsigned short* __restrict__ vt) {
    int h = blockIdx.x >> 7;
    int n0 = (blockIdx.x & 127) << 6;
    __shared__ unsigned short t[64][65];
    int tid = threadIdx.x;
    int col = tid & 63;      // d
    int rr = tid >> 6;       // 0..3
    const float* src = v + ((size_t)(h * NTOK + n0)) * DD;
#pragma unroll
    for (int r = 0; r < 16; ++r) {
        int row = rr + r * 4;   // n local
        t[col][row] = f2bf(src[(size_t)row * DD + col]);
    }
    __syncthreads();
    int d = tid >> 2, ch = tid & 3;
    union { unsigned short u[16]; uint4 q[2]; } tmp;
#pragma unroll
    for (int j = 0; j < 16; ++j) tmp.u[j] = t[d][ch * 16 + j];
    int b = (n0 >> 5) + (ch >> 1);
    unsigned short* dst = vt + ((size_t)(h * 256 + b)) * 2048 + d * 32 + (ch & 1) * 16;
    ((uint4*)dst)[0] = tmp.q[0];
    ((uint4*)dst)[1] = tmp.q[1];
}

// ---------------- level-1 pool from bf16 sources ----------------
__global__ __launch_bounds__(256) void pool1_b(const unsigned short* __restrict__ Kb,
                                               const unsigned short* __restrict__ Vtb,
                                               unsigned short* __restrict__ k1,
                                               unsigned short* __restrict__ vt1) {
    int tid = blockIdx.x * blockDim.x + threadIdx.x;   // NH*1024*64
    int d = tid & 63;
    int c = (tid >> 6) & 1023;
    int h = tid >> 16;
    const unsigned short* kp = Kb + ((size_t)(h * NTOK + c * 8)) * DD + d;
    float ks = 0.f;
#pragma unroll
    for (int r = 0; r < 8; ++r) ks += bf2f(kp[(size_t)r * DD]);
    // V: 8 consecutive raw tokens inside one V-block row
    const unsigned short* vp = Vtb + ((size_t)((h * 256 + (c >> 2)) * DD + d)) * 32 + 8 * (c & 3);
    union { unsigned short u[8]; uint4 q; } vv;
    vv.q = *(const uint4*)(const void*)vp;
    float vs = 0.f;
#pragma unroll
    for (int j = 0; j < 8; ++j) vs += bf2f(vv.u[j]);
    k1[((size_t)(h * 1024 + c)) * DD + d] = f2bf(ks * 0.125f);
    vt1[((size_t)((h * 32 + (c >> 5)) * DD + d)) * 32 + (c & 31)] = f2bf(vs * 0.125f);
}

// ---------------- level-2 pool ----------------
__global__ __launch_bounds__(256) void pool2_b(const unsigned short* __restrict__ k1,
                                               const unsigned short* __restrict__ vt1,
                                               unsigned short* __restrict__ k2,
                                               unsigned short* __restrict__ vt2) {
    int tid = blockIdx.x * blockDim.x + threadIdx.x;   // NH*128*64
    int d = tid & 63;
    int c = (tid >> 6) & 127;
    int h = tid >> 13;
    const unsigned short* kp = k1 + ((size_t)(h * 1024 + c * 8)) * DD + d;
    float ks = 0.f;
#pragma unroll
    for (int r = 0; r < 8; ++r) ks += bf2f(kp[(size_t)r * DD]);
    const unsigned short* vp = vt1 + ((size_t)((h * 32 + (c >> 2)) * DD + d)) * 32 + 8 * (c & 3);
    union { unsigned short u[8]; uint4 q; } vv;
    vv.q = *(const uint4*)(const void*)vp;
    float vs = 0.f;
#pragma unroll
    for (int j = 0; j < 8; ++j) vs += bf2f(vv.u[j]);
    k2[((size_t)(h * 128 + c)) * DD + d] = f2bf(ks * 0.125f);
    vt2[((size_t)((h * 4 + (c >> 5)) * DD + d)) * 32 + (c & 31)] = f2bf(vs * 0.125f);
}

// ---------------- level-3 pool (16 real chunks, padded to 32) ----------------
__global__ __launch_bounds__(256) void pool3_b(const unsigned short* __restrict__ k2,
                                               const unsigned short* __restrict__ vt2,
                                               unsigned short* __restrict__ k3,
                                               unsigned short* __restrict__ vt3) {
    int tid = blockIdx.x * blockDim.x + threadIdx.x;   // NH*32*64
    int d = tid & 63;
    int c = (tid >> 6) & 31;
    int h = tid >> 11;
    float ks = 0.f, vs = 0.f;
    if (c < 16) {
        const unsigned short* kp = k2 + ((size_t)(h * 128 + c * 8)) * DD + d;
#pragma unroll
        for (int r = 0; r < 8; ++r) ks += bf2f(kp[(size_t)r * DD]);
        const unsigned short* vp = vt2 + ((size_t)((h * 4 + (c >> 2)) * DD + d)) * 32 + 8 * (c & 3);
        union { unsigned short u[8]; uint4 q; } vv;
        vv.q = *(const uint4*)(const void*)vp;
#pragma unroll
        for (int j = 0; j < 8; ++j) vs += bf2f(vv.u[j]);
        ks *= 0.125f; vs *= 0.125f;
    }
    k3[((size_t)(h * 32 + c)) * DD + d] = f2bf(ks);
    vt3[((size_t)(h * DD + d)) * 32 + c] = f2bf(vs);
}

// K+V fragments of one 32-key group
struct KV32 { bf16x8 k0, k1, k2, k3, v0, v1, v2, v3; };

// ---------------- one 32-key sub-group, 32 queries (2 tiles) ----------------
// Fixed-m streaming: no per-group max/ballot/rescale. INIT computes m once.
template<bool L0T, bool INIT>
__device__ __forceinline__ void sub32(
    int c0, int Qs, int lgS, float gp, float gps, float& m,
    const KV32& t, int g, int c,
    bf16x8 qa0, bf16x8 qa1, bf16x8 qb0, bf16x8 qb1,
    float& lA, float& lB, f32x4* oA, f32x4* oB)
{
    const int i_qA = Qs + c, i_qB = i_qA + 16;

    __builtin_amdgcn_s_setprio(1);
    f32x4 z = {0.f, 0.f, 0.f, 0.f};
    f32x4 sAA = MFMA(t.k1, qa1, MFMA(t.k0, qa0, z));
    f32x4 sAB = MFMA(t.k3, qa1, MFMA(t.k2, qa0, z));
    f32x4 sBA = MFMA(t.k1, qb1, MFMA(t.k0, qb0, z));
    f32x4 sBB = MFMA(t.k3, qb1, MFMA(t.k2, qb0, z));
    __builtin_amdgcn_s_setprio(0);

    const float negfbA = gps * (float)(8 * g) + gp * (float)((1 << lgS) - 1) - gp * (float)i_qA;
    const float negfbB = negfbA - 16.f * gp;
    float c0f = (float)c0;

    float svA[8], svB[8];
    bool fastA, fastB;
    if (L0T) {
        fastA = (c0 >= Qs - 112) && (c0 + 31 <= Qs);
        fastB = (c0 >= Qs - 96) && (c0 + 31 <= Qs + 16);
    } else {
        int numA = Qs - 128 - ((1 << lgS) - 1);
        int numB = numA + 16;
        fastA = (numA >= 0) && (c0 + 31 <= (numA >> lgS));
        fastB = (numB >= 0) && (c0 + 31 <= (numB >> lgS));
    }
    if (fastA) {
        float u0 = fmaf(gps, c0f, negfbA);
        svA[0] = sAA[0] + u0;
        svA[1] = sAA[1] + fmaf(gps, 1.f, u0);
        svA[2] = sAA[2] + fmaf(gps, 2.f, u0);
        svA[3] = sAA[3] + fmaf(gps, 3.f, u0);
        svA[4] = sAB[0] + fmaf(gps, 4.f, u0);
        svA[5] = sAB[1] + fmaf(gps, 5.f, u0);
        svA[6] = sAB[2] + fmaf(gps, 6.f, u0);
        svA[7] = sAB[3] + fmaf(gps, 7.f, u0);
    } else {
#pragma unroll
        for (int r = 0; r < 4; ++r) {
            int cA = c0 + 8 * g + r, cB = cA + 4;
            int jA = L0T ? cA : (((cA + 1) << lgS) - 1);
            int jB = L0T ? cB : (((cB + 1) << lgS) - 1);
            int dA = i_qA - jA, dB = i_qA - jB;
            bool aA = L0T ? ((unsigned)dA <= 127u) : (dA >= 128);
            bool aB = L0T ? ((unsigned)dB <= 127u) : (dB >= 128);
            svA[r]     = aA ? fmaf(-gp, (float)dA, sAA[r]) : NEGF;
            svA[r + 4] = aB ? fmaf(-gp, (float)dB, sAB[r]) : NEGF;
        }
    }
    if (fastB) {
        float u0 = fmaf(gps, c0f, negfbB);
        svB[0] = sBA[0] + u0;
        svB[1] = sBA[1] + fmaf(gps, 1.f, u0);
        svB[2] = sBA[2] + fmaf(gps, 2.f, u0);
        svB[3] = sBA[3] + fmaf(gps, 3.f, u0);
        svB[4] = sBB[0] + fmaf(gps, 4.f, u0);
        svB[5] = sBB[1] + fmaf(gps, 5.f, u0);
        svB[6] = sBB[2] + fmaf(gps, 6.f, u0);
        svB[7] = sBB[3] + fmaf(gps, 7.f, u0);
    } else {
#pragma unroll
        for (int r = 0; r < 4; ++r) {
            int cA = c0 + 8 * g + r, cB = cA + 4;
            int jA = L0T ? cA : (((cA + 1) << lgS) - 1);
            int jB = L0T ? cB : (((cB + 1) << lgS) - 1);
            int dA = i_qB - jA, dB = i_qB - jB;
            bool aA = L0T ? ((unsigned)dA <= 127u) : (dA >= 128);
            bool aB = L0T ? ((unsigned)dB <= 127u) : (dB >= 128);
            svB[r]     = aA ? fmaf(-gp, (float)dA, sBA[r]) : NEGF;
            svB[r + 4] = aB ? fmaf(-gp, (float)dB, sBB[r]) : NEGF;
        }
    }

    if (INIT) {
        // one-time wave max; frozen afterwards (scores can't exceed it by >127 exp2 units)
        float tm = fmaxf(
            fmaxf(fmaxf(fmaxf(svA[0], svA[1]), fmaxf(svA[2], svA[3])),
                  fmaxf(fmaxf(svA[4], svA[5]), fmaxf(svA[6], svA[7]))),
            fmaxf(fmaxf(fmaxf(svB[0], svB[1]), fmaxf(svB[2], svB[3])),
                  fmaxf(fmaxf(svB[4], svB[5]), fmaxf(svB[6], svB[7]))));
        tm = fmaxf(tm, __shfl_xor(tm, 1));
        tm = fmaxf(tm, __shfl_xor(tm, 2));
        tm = fmaxf(tm, __shfl_xor(tm, 4));
        tm = fmaxf(tm, __shfl_xor(tm, 8));
        tm = fmaxf(tm, __shfl_xor(tm, 16));
        tm = fmaxf(tm, __shfl_xor(tm, 32));
        m = tm;
    }

    union { unsigned u32[4]; bf16x8 v8; } pfA, pfB;
    {
        float p[8];
#pragma unroll
        for (int r = 0; r < 8; ++r) p[r] = EXP2(svA[r] - m);
        lA += ((p[0] + p[1]) + (p[2] + p[3])) + ((p[4] + p[5]) + (p[6] + p[7]));
#pragma unroll
        for (int j = 0; j < 4; ++j)
            asm("v_cvt_pk_bf16_f32 %0, %1, %2" : "=v"(pfA.u32[j]) : "v"(p[2 * j]), "v"(p[2 * j + 1]));
    }
    {
        float p[8];
#pragma unroll
        for (int r = 0; r < 8; ++r) p[r] = EXP2(svB[r] - m);
        lB += ((p[0] + p[1]) + (p[2] + p[3])) + ((p[4] + p[5]) + (p[6] + p[7]));
#pragma unroll
        for (int j = 0; j < 4; ++j)
            asm("v_cvt_pk_bf16_f32 %0, %1, %2" : "=v"(pfB.u32[j]) : "v"(p[2 * j]), "v"(p[2 * j + 1]));
    }

    __builtin_amdgcn_s_setprio(1);
    oA[0] = MFMA(t.v0, pfA.v8, oA[0]);
    oB[0] = MFMA(t.v0, pfB.v8, oB[0]);
    oA[1] = MFMA(t.v1, pfA.v8, oA[1]);
    oB[1] = MFMA(t.v1, pfB.v8, oB[1]);
    oA[2] = MFMA(t.v2, pfA.v8, oA[2]);
    oB[2] = MFMA(t.v2, pfB.v8, oB[2]);
    oA[3] = MFMA(t.v3, pfA.v8, oA[3]);
    oB[3] = MFMA(t.v3, pfB.v8, oB[3]);
    __builtin_amdgcn_s_setprio(0);
}

// ---------------- main attention: 4 independent waves/block, 32 queries/wave ----------------
__global__ __launch_bounds__(256, 3) void attn_mfma(
    const unsigned short* __restrict__ Qb, const unsigned short* __restrict__ Kb,
    const unsigned short* __restrict__ Vtb,
    const unsigned short* __restrict__ K1, const unsigned short* __restrict__ Vt1,
    const unsigned short* __restrict__ K2, const unsigned short* __restrict__ Vt2,
    const unsigned short* __restrict__ K3, const unsigned short* __restrict__ Vt3,
    const float* __restrict__ gam, float* __restrict__ out) {
    const int lane = threadIdx.x & 63;
    const int wid = threadIdx.x >> 6;
    const int h = blockIdx.x & 15;        // head->XCD pinning for L2 locality
    const int qt = blockIdx.x >> 4;       // 0..63
    const int Qs = (qt << 7) + wid * 32;
    const int g = lane >> 4;
    const int c = lane & 15;

    const float g0 = gam[0] * LOG2E, g1 = gam[1] * LOG2E;
    const float g2 = gam[2] * LOG2E, g3 = gam[3] * LOG2E;

    // per-lane K/V source bases (key-permuted tile layout)
    const unsigned short* KbH = Kb + (size_t)h * NTOK * DD + ((size_t)(8 * (c >> 2) + (c & 3))) * DD + g * 8;
    const unsigned short* VtH = Vtb + (size_t)h * 256 * 2048 + c * 32 + g * 8;
    const unsigned short* K1H = K1 + (size_t)h * 1024 * DD + ((size_t)(8 * (c >> 2) + (c & 3))) * DD + g * 8;
    const unsigned short* V1H = Vt1 + (size_t)h * 32 * 2048 + c * 32 + g * 8;
    const unsigned short* K2H = K2 + (size_t)h * 128 * DD + ((size_t)(8 * (c >> 2) + (c & 3))) * DD + g * 8;
    const unsigned short* V2H = Vt2 + (size_t)h * 4 * 2048 + c * 32 + g * 8;
    const unsigned short* K3H = K3 + (size_t)h * 32 * DD + ((size_t)(8 * (c >> 2) + (c & 3))) * DD + g * 8;
    const unsigned short* V3H = Vt3 + (size_t)h * 2048 + c * 32 + g * 8;

    auto LOADKV = [&](const unsigned short* Kh, const unsigned short* Vh, int c0) -> KV32 {
        KV32 r;
        const unsigned short* ka = Kh + (size_t)c0 * DD;
        r.k0 = *(const bf16x8*)(const void*)(ka);
        r.k1 = *(const bf16x8*)(const void*)(ka + 32);
        r.k2 = *(const bf16x8*)(const void*)(ka + 4 * DD);
        r.k3 = *(const bf16x8*)(const void*)(ka + 4 * DD + 32);
        const unsigned short* va = Vh + (size_t)(c0 >> 5) * 2048;
        r.v0 = *(const bf16x8*)(const void*)(va);
        r.v1 = *(const bf16x8*)(const void*)(va + 512);
        r.v2 = *(const bf16x8*)(const void*)(va + 1024);
        r.v3 = *(const bf16x8*)(const void*)(va + 1536);
        return r;
    };

    // Q fragments
    const unsigned short* QrowA = Qb + ((size_t)(h * NTOK + Qs + c)) * DD;
    bf16x8 qa0 = *(const bf16x8*)(const void*)(QrowA + g * 8);
    bf16x8 qa1 = *(const bf16x8*)(const void*)(QrowA + 32 + g * 8);
    const unsigned short* QrowB = QrowA + 16 * DD;
    bf16x8 qb0 = *(const bf16x8*)(const void*)(QrowB + g * 8);
    bf16x8 qb1 = *(const bf16x8*)(const void*)(QrowB + 32 + g * 8);

    f32x4 oA[4], oB[4];
#pragma unroll
    for (int t = 0; t < 4; ++t) { oA[t] = (f32x4){0.f,0.f,0.f,0.f}; oB[t] = (f32x4){0.f,0.f,0.f,0.f}; }
    float m = NEGF, lA = 0.f, lB = 0.f;

    // ---- level 0, first group (keys [Qs..Qs+31], always has each query's diagonal): INIT m ----
    {
        KV32 t = LOADKV(KbH, VtH, Qs);
        sub32<true, true>(Qs, Qs, 0, g0, g0, m, t, g, c, qa0, qa1, qb0, qb1, lA, lB, oA, oB);
    }
    // ---- level 0, remaining window, paired 64-key iterations ----
    {
        int lo0 = Qs - 127; if (lo0 < 0) lo0 = 0; lo0 &= ~31;
        int c0 = Qs - 64;
        while (c0 >= lo0) {
            KV32 a = LOADKV(KbH, VtH, c0 + 32);
            KV32 b = LOADKV(KbH, VtH, c0);
            sub32<true, false>(c0 + 32, Qs, 0, g0, g0, m, a, g, c, qa0, qa1, qb0, qb1, lA, lB, oA, oB);
            sub32<true, false>(c0,      Qs, 0, g0, g0, m, b, g, c, qa0, qa1, qb0, qb1, lA, lB, oA, oB);
            c0 -= 64;
        }
        if (c0 + 32 >= lo0) {
            KV32 a = LOADKV(KbH, VtH, c0 + 32);
            sub32<true, false>(c0 + 32, Qs, 0, g0, g0, m, a, g, c, qa0, qa1, qb0, qb1, lA, lB, oA, oB);
        }
    }
    // ---- level 1: 64-key iterations ----
    {
        int cm = Qs - 104;                 // (Qs+31)-128-7
        if (cm >= 0) {
            for (int c0 = (cm / 8) & ~63; c0 >= 0; c0 -= 64) {
                KV32 a = LOADKV(K1H, V1H, c0 + 32);
                KV32 b = LOADKV(K1H, V1H, c0);
                sub32<false, false>(c0 + 32, Qs, 3, g1, g1 * 8.f, m, a, g, c, qa0, qa1, qb0, qb1, lA, lB, oA, oB);
                sub32<false, false>(c0,      Qs, 3, g1, g1 * 8.f, m, b, g, c, qa0, qa1, qb0, qb1, lA, lB, oA, oB);
            }
        }
    }
    // ---- level 2: 64-key iterations (<=2) ----
    {
        int cm = Qs - 160;                 // (Qs+31)-128-63
        if (cm >= 0) {
            for (int c0 = ((cm / 64) & ~63); c0 >= 0; c0 -= 64) {
                KV32 a = LOADKV(K2H, V2H, c0 + 32);
                KV32 b = LOADKV(K2H, V2H, c0);
                sub32<false, false>(c0 + 32, Qs, 6, g2, g2 * 64.f, m, a, g, c, qa0, qa1, qb0, qb1, lA, lB, oA, oB);
                sub32<false, false>(c0,      Qs, 6, g2, g2 * 64.f, m, b, g, c, qa0, qa1, qb0, qb1, lA, lB, oA, oB);
            }
        }
    }
    // ---- level 3: single 32-chunk group (16 real, padded; mask guards the pad) ----
    {
        int cm = Qs - 608;                 // (Qs+31)-128-511
        if (cm >= 0) {
            KV32 t = LOADKV(K3H, V3H, 0);
            sub32<false, false>(0, Qs, 9, g3, g3 * 512.f, m, t, g, c, qa0, qa1, qb0, qb1, lA, lB, oA, oB);
        }
    }

    // final l reduce over the 4 g-lanes of each query column
    float ltA = lA + __shfl_xor(lA, 16); ltA += __shfl_xor(ltA, 32);
    float ltB = lB + __shfl_xor(lB, 16); ltB += __shfl_xor(ltB, 32);
    float invA = 1.0f / fmaxf(ltA, 1e-8f);
    float invB = 1.0f / fmaxf(ltB, 1e-8f);

    float* orowA = out + ((size_t)(h * NTOK + Qs + c)) * DD;
    float* orowB = orowA + 16 * DD;
#pragma unroll
    for (int db = 0; db < 4; ++db) {
        float4 x;
        x.x = oA[db][0] * invA; x.y = oA[db][1] * invA;
        x.z = oA[db][2] * invA; x.w = oA[db][3] * invA;
        *(float4*)(orowA + db * 16 + 4 * g) = x;
        float4 y;
        y.x = oB[db][0] * invB; y.y = oB[db][1] * invB;
        y.z = oB[db][2] * invB; y.w = oB[db][3] * invB;
        *(float4*)(orowB + db * 16 + 4 * g) = y;
    }
}

extern "C" void kernel_launch(void* const* d_in, const int* in_sizes, int n_in,
                              void* d_out, int out_size, void* d_ws, size_t ws_size,
                              hipStream_t stream) {
    const float* q = (const float*)d_in[0];
    const float* k = (const float*)d_in[1];
    const float* v = (const float*)d_in[2];
    const float* gam = (const float*)d_in[3];
    float* out = (float*)d_out;

    char* w = (char*)d_ws;
    const size_t bigN = (size_t)NH * NTOK * DD * sizeof(unsigned short);
    unsigned short* Qbuf = (unsigned short*)w;  w += bigN;
    unsigned short* Kbuf = (unsigned short*)w;  w += bigN;
    unsigned short* Vtb  = (unsigned short*)w;  w += bigN;                       // blocked
    unsigned short* K1   = (unsigned short*)w;  w += (size_t)NH * 1024 * DD * 2;
    unsigned short* Vt1  = (unsigned short*)w;  w += (size_t)NH * 1024 * DD * 2; // blocked
    unsigned short* K2   = (unsigned short*)w;  w += (size_t)NH * 128 * DD * 2;
    unsigned short* Vt2  = (unsigned short*)w;  w += (size_t)NH * 128 * DD * 2;  // blocked
    unsigned short* K3   = (unsigned short*)w;  w += (size_t)NH * 32 * DD * 2;
    unsigned short* Vt3  = (unsigned short*)w;  w += (size_t)NH * 32 * DD * 2;   // blocked

    int n8 = NH * NTOK * DD / 8;
    const float qscale = 0.125f * LOG2E;   // fold softmax scale + log2e into Q
    cvt_qk<<<2 * n8 / 256, 256, 0, stream>>>(q, k, Qbuf, Kbuf, qscale, n8);
    transpose_v<<<NH * (NTOK / 64), 256, 0, stream>>>(v, Vtb);
    pool1_b<<<NH * 1024 * DD / 256, 256, 0, stream>>>(Kbuf, Vtb, K1, Vt1);
    pool2_b<<<NH * 128 * DD / 256, 256, 0, stream>>>(K1, Vt1, K2, Vt2);
    pool3_b<<<NH * 32 * DD / 256, 256, 0, stream>>>(K2, Vt2, K3, Vt3);

    attn_mfma<<<NH * 64, 256, 0, stream>>>(Qbuf, Kbuf, Vtb, K1, Vt1, K2, Vt2, K3, Vt3, gam, out);
}

// Round 10
// 124.887 us; speedup vs baseline: 2.6868x; 1.0615x over previous
//
#include <hip/hip_runtime.h>

#define NTOK 8192
#define NH 16
#define DD 64
#define NEGF -1e30f
#define LOG2E 1.4426950408889634f

typedef __attribute__((ext_vector_type(8))) short bf16x8;
typedef __attribute__((ext_vector_type(4))) float f32x4;

#define MFMA(a, b, c) __builtin_amdgcn_mfma_f32_16x16x32_bf16((a), (b), (c), 0, 0, 0)
#define EXP2(x) __builtin_amdgcn_exp2f(x)

static __device__ __forceinline__ unsigned short f2bf(float x) {
    union { float f; unsigned u; } c; c.f = x;
    unsigned r = (c.u + 0x7FFFu + ((c.u >> 16) & 1u)) >> 16;
    return (unsigned short)r;
}
static __device__ __forceinline__ float bf2f(unsigned short x) {
    union { unsigned u; float f; } c; c.u = ((unsigned)x) << 16;
    return c.f;
}

// ---------------- fused prep: k fp32->bf16 row-major, v fp32 -> blocked vt ----------------
__global__ __launch_bounds__(256) void prep_kv(const float* __restrict__ k, const float* __restrict__ v,
                                               unsigned short* __restrict__ Kb,
                                               unsigned short* __restrict__ vt) {
    int h = blockIdx.x >> 7;
    int n0 = (blockIdx.x & 127) << 6;
    int tid = threadIdx.x;

    // --- k convert: thread = (row = tid>>2, 16 cols at (tid&3)*16) ---
    {
        int row = tid >> 2, cs = (tid & 3) * 16;
        const float* src = k + ((size_t)(h * NTOK + n0 + row)) * DD + cs;
        unsigned short* dst = Kb + ((size_t)(h * NTOK + n0 + row)) * DD + cs;
        float4 f0 = ((const float4*)src)[0], f1 = ((const float4*)src)[1];
        float4 f2 = ((const float4*)src)[2], f3 = ((const float4*)src)[3];
        union { unsigned short u[16]; uint4 q4[2]; } o;
        o.u[0] = f2bf(f0.x); o.u[1] = f2bf(f0.y); o.u[2] = f2bf(f0.z); o.u[3] = f2bf(f0.w);
        o.u[4] = f2bf(f1.x); o.u[5] = f2bf(f1.y); o.u[6] = f2bf(f1.z); o.u[7] = f2bf(f1.w);
        o.u[8] = f2bf(f2.x); o.u[9] = f2bf(f2.y); o.u[10] = f2bf(f2.z); o.u[11] = f2bf(f2.w);
        o.u[12] = f2bf(f3.x); o.u[13] = f2bf(f3.y); o.u[14] = f2bf(f3.z); o.u[15] = f2bf(f3.w);
        ((uint4*)dst)[0] = o.q4[0];
        ((uint4*)dst)[1] = o.q4[1];
    }

    // --- v transpose into blocked vt[h][n>>5][d][n&31] ---
    __shared__ unsigned short t[64][65];
    int col = tid & 63;      // d
    int rr = tid >> 6;       // 0..3
    const float* src = v + ((size_t)(h * NTOK + n0)) * DD;
#pragma unroll
    for (int r = 0; r < 16; ++r) {
        int row = rr + r * 4;   // n local
        t[col][row] = f2bf(src[(size_t)row * DD + col]);
    }
    __syncthreads();
    int d = tid >> 2, ch = tid & 3;
    union { unsigned short u[16]; uint4 q[2]; } tmp;
#pragma unroll
    for (int j = 0; j < 16; ++j) tmp.u[j] = t[d][ch * 16 + j];
    int b = (n0 >> 5) + (ch >> 1);
    unsigned short* dst = vt + ((size_t)(h * 256 + b)) * 2048 + d * 32 + (ch & 1) * 16;
    ((uint4*)dst)[0] = tmp.q[0];
    ((uint4*)dst)[1] = tmp.q[1];
}

// ---------------- level-1 pool from bf16 sources ----------------
__global__ __launch_bounds__(256) void pool1_b(const unsigned short* __restrict__ Kb,
                                               const unsigned short* __restrict__ Vtb,
                                               unsigned short* __restrict__ k1,
                                               unsigned short* __restrict__ vt1) {
    int tid = blockIdx.x * blockDim.x + threadIdx.x;   // NH*1024*64
    int d = tid & 63;
    int c = (tid >> 6) & 1023;
    int h = tid >> 16;
    const unsigned short* kp = Kb + ((size_t)(h * NTOK + c * 8)) * DD + d;
    float ks = 0.f;
#pragma unroll
    for (int r = 0; r < 8; ++r) ks += bf2f(kp[(size_t)r * DD]);
    const unsigned short* vp = Vtb + ((size_t)((h * 256 + (c >> 2)) * DD + d)) * 32 + 8 * (c & 3);
    union { unsigned short u[8]; uint4 q; } vv;
    vv.q = *(const uint4*)(const void*)vp;
    float vs = 0.f;
#pragma unroll
    for (int j = 0; j < 8; ++j) vs += bf2f(vv.u[j]);
    k1[((size_t)(h * 1024 + c)) * DD + d] = f2bf(ks * 0.125f);
    vt1[((size_t)((h * 32 + (c >> 5)) * DD + d)) * 32 + (c & 31)] = f2bf(vs * 0.125f);
}

// ---------------- level-2 pool ----------------
__global__ __launch_bounds__(256) void pool2_b(const unsigned short* __restrict__ k1,
                                               const unsigned short* __restrict__ vt1,
                                               unsigned short* __restrict__ k2,
                                               unsigned short* __restrict__ vt2) {
    int tid = blockIdx.x * blockDim.x + threadIdx.x;   // NH*128*64
    int d = tid & 63;
    int c = (tid >> 6) & 127;
    int h = tid >> 13;
    const unsigned short* kp = k1 + ((size_t)(h * 1024 + c * 8)) * DD + d;
    float ks = 0.f;
#pragma unroll
    for (int r = 0; r < 8; ++r) ks += bf2f(kp[(size_t)r * DD]);
    const unsigned short* vp = vt1 + ((size_t)((h * 32 + (c >> 2)) * DD + d)) * 32 + 8 * (c & 3);
    union { unsigned short u[8]; uint4 q; } vv;
    vv.q = *(const uint4*)(const void*)vp;
    float vs = 0.f;
#pragma unroll
    for (int j = 0; j < 8; ++j) vs += bf2f(vv.u[j]);
    k2[((size_t)(h * 128 + c)) * DD + d] = f2bf(ks * 0.125f);
    vt2[((size_t)((h * 4 + (c >> 5)) * DD + d)) * 32 + (c & 31)] = f2bf(vs * 0.125f);
}

// ---------------- level-3 pool (16 real chunks, padded to 32) ----------------
__global__ __launch_bounds__(256) void pool3_b(const unsigned short* __restrict__ k2,
                                               const unsigned short* __restrict__ vt2,
                                               unsigned short* __restrict__ k3,
                                               unsigned short* __restrict__ vt3) {
    int tid = blockIdx.x * blockDim.x + threadIdx.x;   // NH*32*64
    int d = tid & 63;
    int c = (tid >> 6) & 31;
    int h = tid >> 11;
    float ks = 0.f, vs = 0.f;
    if (c < 16) {
        const unsigned short* kp = k2 + ((size_t)(h * 128 + c * 8)) * DD + d;
#pragma unroll
        for (int r = 0; r < 8; ++r) ks += bf2f(kp[(size_t)r * DD]);
        const unsigned short* vp = vt2 + ((size_t)((h * 4 + (c >> 2)) * DD + d)) * 32 + 8 * (c & 3);
        union { unsigned short u[8]; uint4 q; } vv;
        vv.q = *(const uint4*)(const void*)vp;
#pragma unroll
        for (int j = 0; j < 8; ++j) vs += bf2f(vv.u[j]);
        ks *= 0.125f; vs *= 0.125f;
    }
    k3[((size_t)(h * 32 + c)) * DD + d] = f2bf(ks);
    vt3[((size_t)(h * DD + d)) * 32 + c] = f2bf(vs);
}

// K+V fragments of one 32-key group
struct KV32 { bf16x8 k0, k1, k2, k3, v0, v1, v2, v3; };

// ---------------- one 32-key sub-group, 32 queries (2 tiles) ----------------
// Fixed-m streaming: no per-group max/ballot/rescale. INIT computes m once.
template<bool L0T, bool INIT>
__device__ __forceinline__ void sub32(
    int c0, int Qs, int lgS, float gp, float gps, float& m,
    const KV32& t, int g, int c,
    bf16x8 qa0, bf16x8 qa1, bf16x8 qb0, bf16x8 qb1,
    float& lA, float& lB, f32x4* oA, f32x4* oB)
{
    const int i_qA = Qs + c, i_qB = i_qA + 16;

    __builtin_amdgcn_s_setprio(1);
    f32x4 z = {0.f, 0.f, 0.f, 0.f};
    f32x4 sAA = MFMA(t.k1, qa1, MFMA(t.k0, qa0, z));
    f32x4 sAB = MFMA(t.k3, qa1, MFMA(t.k2, qa0, z));
    f32x4 sBA = MFMA(t.k1, qb1, MFMA(t.k0, qb0, z));
    f32x4 sBB = MFMA(t.k3, qb1, MFMA(t.k2, qb0, z));
    __builtin_amdgcn_s_setprio(0);

    const float negfbA = gps * (float)(8 * g) + gp * (float)((1 << lgS) - 1) - gp * (float)i_qA;
    const float negfbB = negfbA - 16.f * gp;
    float c0f = (float)c0;

    float svA[8], svB[8];
    bool fastA, fastB;
    if (L0T) {
        fastA = (c0 >= Qs - 112) && (c0 + 31 <= Qs);
        fastB = (c0 >= Qs - 96) && (c0 + 31 <= Qs + 16);
    } else {
        int numA = Qs - 128 - ((1 << lgS) - 1);
        int numB = numA + 16;
        fastA = (numA >= 0) && (c0 + 31 <= (numA >> lgS));
        fastB = (numB >= 0) && (c0 + 31 <= (numB >> lgS));
    }
    if (fastA) {
        float u0 = fmaf(gps, c0f, negfbA);
        svA[0] = sAA[0] + u0;
        svA[1] = sAA[1] + fmaf(gps, 1.f, u0);
        svA[2] = sAA[2] + fmaf(gps, 2.f, u0);
        svA[3] = sAA[3] + fmaf(gps, 3.f, u0);
        svA[4] = sAB[0] + fmaf(gps, 4.f, u0);
        svA[5] = sAB[1] + fmaf(gps, 5.f, u0);
        svA[6] = sAB[2] + fmaf(gps, 6.f, u0);
        svA[7] = sAB[3] + fmaf(gps, 7.f, u0);
    } else {
#pragma unroll
        for (int r = 0; r < 4; ++r) {
            int cA = c0 + 8 * g + r, cB = cA + 4;
            int jA = L0T ? cA : (((cA + 1) << lgS) - 1);
            int jB = L0T ? cB : (((cB + 1) << lgS) - 1);
            int dA = i_qA - jA, dB = i_qA - jB;
            bool aA = L0T ? ((unsigned)dA <= 127u) : (dA >= 128);
            bool aB = L0T ? ((unsigned)dB <= 127u) : (dB >= 128);
            svA[r]     = aA ? fmaf(-gp, (float)dA, sAA[r]) : NEGF;
            svA[r + 4] = aB ? fmaf(-gp, (float)dB, sAB[r]) : NEGF;
        }
    }
    if (fastB) {
        float u0 = fmaf(gps, c0f, negfbB);
        svB[0] = sBA[0] + u0;
        svB[1] = sBA[1] + fmaf(gps, 1.f, u0);
        svB[2] = sBA[2] + fmaf(gps, 2.f, u0);
        svB[3] = sBA[3] + fmaf(gps, 3.f, u0);
        svB[4] = sBB[0] + fmaf(gps, 4.f, u0);
        svB[5] = sBB[1] + fmaf(gps, 5.f, u0);
        svB[6] = sBB[2] + fmaf(gps, 6.f, u0);
        svB[7] = sBB[3] + fmaf(gps, 7.f, u0);
    } else {
#pragma unroll
        for (int r = 0; r < 4; ++r) {
            int cA = c0 + 8 * g + r, cB = cA + 4;
            int jA = L0T ? cA : (((cA + 1) << lgS) - 1);
            int jB = L0T ? cB : (((cB + 1) << lgS) - 1);
            int dA = i_qB - jA, dB = i_qB - jB;
            bool aA = L0T ? ((unsigned)dA <= 127u) : (dA >= 128);
            bool aB = L0T ? ((unsigned)dB <= 127u) : (dB >= 128);
            svB[r]     = aA ? fmaf(-gp, (float)dA, sBA[r]) : NEGF;
            svB[r + 4] = aB ? fmaf(-gp, (float)dB, sBB[r]) : NEGF;
        }
    }

    if (INIT) {
        // one-time wave max; frozen afterwards (scores can't exceed it by >127 exp2 units)
        float tm = fmaxf(
            fmaxf(fmaxf(fmaxf(svA[0], svA[1]), fmaxf(svA[2], svA[3])),
                  fmaxf(fmaxf(svA[4], svA[5]), fmaxf(svA[6], svA[7]))),
            fmaxf(fmaxf(fmaxf(svB[0], svB[1]), fmaxf(svB[2], svB[3])),
                  fmaxf(fmaxf(svB[4], svB[5]), fmaxf(svB[6], svB[7]))));
        tm = fmaxf(tm, __shfl_xor(tm, 1));
        tm = fmaxf(tm, __shfl_xor(tm, 2));
        tm = fmaxf(tm, __shfl_xor(tm, 4));
        tm = fmaxf(tm, __shfl_xor(tm, 8));
        tm = fmaxf(tm, __shfl_xor(tm, 16));
        tm = fmaxf(tm, __shfl_xor(tm, 32));
        m = tm;
    }

    union { unsigned u32[4]; bf16x8 v8; } pfA, pfB;
    {
        float p[8];
#pragma unroll
        for (int r = 0; r < 8; ++r) p[r] = EXP2(svA[r] - m);
        lA += ((p[0] + p[1]) + (p[2] + p[3])) + ((p[4] + p[5]) + (p[6] + p[7]));
#pragma unroll
        for (int j = 0; j < 4; ++j)
            asm("v_cvt_pk_bf16_f32 %0, %1, %2" : "=v"(pfA.u32[j]) : "v"(p[2 * j]), "v"(p[2 * j + 1]));
    }
    {
        float p[8];
#pragma unroll
        for (int r = 0; r < 8; ++r) p[r] = EXP2(svB[r] - m);
        lB += ((p[0] + p[1]) + (p[2] + p[3])) + ((p[4] + p[5]) + (p[6] + p[7]));
#pragma unroll
        for (int j = 0; j < 4; ++j)
            asm("v_cvt_pk_bf16_f32 %0, %1, %2" : "=v"(pfB.u32[j]) : "v"(p[2 * j]), "v"(p[2 * j + 1]));
    }

    __builtin_amdgcn_s_setprio(1);
    oA[0] = MFMA(t.v0, pfA.v8, oA[0]);
    oB[0] = MFMA(t.v0, pfB.v8, oB[0]);
    oA[1] = MFMA(t.v1, pfA.v8, oA[1]);
    oB[1] = MFMA(t.v1, pfB.v8, oB[1]);
    oA[2] = MFMA(t.v2, pfA.v8, oA[2]);
    oB[2] = MFMA(t.v2, pfB.v8, oB[2]);
    oA[3] = MFMA(t.v3, pfA.v8, oA[3]);
    oB[3] = MFMA(t.v3, pfB.v8, oB[3]);
    __builtin_amdgcn_s_setprio(0);
}

// ---------------- main attention: 4 independent waves/block, mirror-paired q-tiles ----------------
__global__ __launch_bounds__(256, 3) void attn_mfma(
    const float* __restrict__ q, const unsigned short* __restrict__ Kb,
    const unsigned short* __restrict__ Vtb,
    const unsigned short* __restrict__ K1, const unsigned short* __restrict__ Vt1,
    const unsigned short* __restrict__ K2, const unsigned short* __restrict__ Vt2,
    const unsigned short* __restrict__ K3, const unsigned short* __restrict__ Vt3,
    const float* __restrict__ gam, float* __restrict__ out) {
    const int lane = threadIdx.x & 63;
    const int wid = threadIdx.x >> 6;
    const int h = blockIdx.x & 15;        // head->XCD pinning for L2 locality
    const int idx = blockIdx.x >> 4;      // 0..63
    // mirror pairing: waves 0-1 -> queries idx*64.. ; waves 2-3 -> (127-idx)*64..
    // per-block work = work(early tile) + work(late tile) ~ constant -> no tail
    const int base = (wid < 2) ? (idx << 6) : ((127 - idx) << 6);
    const int Qs = base + (wid & 1) * 32;
    const int g = lane >> 4;
    const int c = lane & 15;

    const float g0 = gam[0] * LOG2E, g1 = gam[1] * LOG2E;
    const float g2 = gam[2] * LOG2E, g3 = gam[3] * LOG2E;

    // per-lane K/V source bases (key-permuted tile layout)
    const unsigned short* KbH = Kb + (size_t)h * NTOK * DD + ((size_t)(8 * (c >> 2) + (c & 3))) * DD + g * 8;
    const unsigned short* VtH = Vtb + (size_t)h * 256 * 2048 + c * 32 + g * 8;
    const unsigned short* K1H = K1 + (size_t)h * 1024 * DD + ((size_t)(8 * (c >> 2) + (c & 3))) * DD + g * 8;
    const unsigned short* V1H = Vt1 + (size_t)h * 32 * 2048 + c * 32 + g * 8;
    const unsigned short* K2H = K2 + (size_t)h * 128 * DD + ((size_t)(8 * (c >> 2) + (c & 3))) * DD + g * 8;
    const unsigned short* V2H = Vt2 + (size_t)h * 4 * 2048 + c * 32 + g * 8;
    const unsigned short* K3H = K3 + (size_t)h * 32 * DD + ((size_t)(8 * (c >> 2) + (c & 3))) * DD + g * 8;
    const unsigned short* V3H = Vt3 + (size_t)h * 2048 + c * 32 + g * 8;

    auto LOADKV = [&](const unsigned short* Kh, const unsigned short* Vh, int c0) -> KV32 {
        KV32 r;
        const unsigned short* ka = Kh + (size_t)c0 * DD;
        r.k0 = *(const bf16x8*)(const void*)(ka);
        r.k1 = *(const bf16x8*)(const void*)(ka + 32);
        r.k2 = *(const bf16x8*)(const void*)(ka + 4 * DD);
        r.k3 = *(const bf16x8*)(const void*)(ka + 4 * DD + 32);
        const unsigned short* va = Vh + (size_t)(c0 >> 5) * 2048;
        r.v0 = *(const bf16x8*)(const void*)(va);
        r.v1 = *(const bf16x8*)(const void*)(va + 512);
        r.v2 = *(const bf16x8*)(const void*)(va + 1024);
        r.v3 = *(const bf16x8*)(const void*)(va + 1536);
        return r;
    };

    // Q fragments: load fp32, scale, pack to bf16 in-kernel (Qb buffer eliminated)
    const float qsc = 0.125f * LOG2E;
    bf16x8 qa0, qa1, qb0, qb1;
    {
        const float* qrA = q + ((size_t)(h * NTOK + Qs + c)) * DD;
        const float* qrB = qrA + 16 * DD;
        float4 a0 = *(const float4*)(qrA + g * 8),      a1 = *(const float4*)(qrA + g * 8 + 4);
        float4 a2 = *(const float4*)(qrA + 32 + g * 8), a3 = *(const float4*)(qrA + 32 + g * 8 + 4);
        float4 b0 = *(const float4*)(qrB + g * 8),      b1 = *(const float4*)(qrB + g * 8 + 4);
        float4 b2 = *(const float4*)(qrB + 32 + g * 8), b3 = *(const float4*)(qrB + 32 + g * 8 + 4);
        union { unsigned u32[4]; bf16x8 v8; } p0, p1, p2, p3;
        asm("v_cvt_pk_bf16_f32 %0, %1, %2" : "=v"(p0.u32[0]) : "v"(a0.x * qsc), "v"(a0.y * qsc));
        asm("v_cvt_pk_bf16_f32 %0, %1, %2" : "=v"(p0.u32[1]) : "v"(a0.z * qsc), "v"(a0.w * qsc));
        asm("v_cvt_pk_bf16_f32 %0, %1, %2" : "=v"(p0.u32[2]) : "v"(a1.x * qsc), "v"(a1.y * qsc));
        asm("v_cvt_pk_bf16_f32 %0, %1, %2" : "=v"(p0.u32[3]) : "v"(a1.z * qsc), "v"(a1.w * qsc));
        asm("v_cvt_pk_bf16_f32 %0, %1, %2" : "=v"(p1.u32[0]) : "v"(a2.x * qsc), "v"(a2.y * qsc));
        asm("v_cvt_pk_bf16_f32 %0, %1, %2" : "=v"(p1.u32[1]) : "v"(a2.z * qsc), "v"(a2.w * qsc));
        asm("v_cvt_pk_bf16_f32 %0, %1, %2" : "=v"(p1.u32[2]) : "v"(a3.x * qsc), "v"(a3.y * qsc));
        asm("v_cvt_pk_bf16_f32 %0, %1, %2" : "=v"(p1.u32[3]) : "v"(a3.z * qsc), "v"(a3.w * qsc));
        asm("v_cvt_pk_bf16_f32 %0, %1, %2" : "=v"(p2.u32[0]) : "v"(b0.x * qsc), "v"(b0.y * qsc));
        asm("v_cvt_pk_bf16_f32 %0, %1, %2" : "=v"(p2.u32[1]) : "v"(b0.z * qsc), "v"(b0.w * qsc));
        asm("v_cvt_pk_bf16_f32 %0, %1, %2" : "=v"(p2.u32[2]) : "v"(b1.x * qsc), "v"(b1.y * qsc));
        asm("v_cvt_pk_bf16_f32 %0, %1, %2" : "=v"(p2.u32[3]) : "v"(b1.z * qsc), "v"(b1.w * qsc));
        asm("v_cvt_pk_bf16_f32 %0, %1, %2" : "=v"(p3.u32[0]) : "v"(b2.x * qsc), "v"(b2.y * qsc));
        asm("v_cvt_pk_bf16_f32 %0, %1, %2" : "=v"(p3.u32[1]) : "v"(b2.z * qsc), "v"(b2.w * qsc));
        asm("v_cvt_pk_bf16_f32 %0, %1, %2" : "=v"(p3.u32[2]) : "v"(b3.x * qsc), "v"(b3.y * qsc));
        asm("v_cvt_pk_bf16_f32 %0, %1, %2" : "=v"(p3.u32[3]) : "v"(b3.z * qsc), "v"(b3.w * qsc));
        qa0 = p0.v8; qa1 = p1.v8; qb0 = p2.v8; qb1 = p3.v8;
    }

    f32x4 oA[4], oB[4];
#pragma unroll
    for (int t = 0; t < 4; ++t) { oA[t] = (f32x4){0.f,0.f,0.f,0.f}; oB[t] = (f32x4){0.f,0.f,0.f,0.f}; }
    float m = NEGF, lA = 0.f, lB = 0.f;

    // ---- level 0, first group (keys [Qs..Qs+31], always has each query's diagonal): INIT m ----
    {
        KV32 t = LOADKV(KbH, VtH, Qs);
        sub32<true, true>(Qs, Qs, 0, g0, g0, m, t, g, c, qa0, qa1, qb0, qb1, lA, lB, oA, oB);
    }
    // ---- level 0, remaining window, paired 64-key iterations ----
    {
        int lo0 = Qs - 127; if (lo0 < 0) lo0 = 0; lo0 &= ~31;
        int c0 = Qs - 64;
        while (c0 >= lo0) {
            KV32 a = LOADKV(KbH, VtH, c0 + 32);
            KV32 b = LOADKV(KbH, VtH, c0);
            sub32<true, false>(c0 + 32, Qs, 0, g0, g0, m, a, g, c, qa0, qa1, qb0, qb1, lA, lB, oA, oB);
            sub32<true, false>(c0,      Qs, 0, g0, g0, m, b, g, c, qa0, qa1, qb0, qb1, lA, lB, oA, oB);
            c0 -= 64;
        }
        if (c0 + 32 >= lo0) {
            KV32 a = LOADKV(KbH, VtH, c0 + 32);
            sub32<true, false>(c0 + 32, Qs, 0, g0, g0, m, a, g, c, qa0, qa1, qb0, qb1, lA, lB, oA, oB);
        }
    }
    // ---- level 1: 64-key iterations ----
    {
        int cm = Qs - 104;                 // (Qs+31)-128-7
        if (cm >= 0) {
            for (int c0 = (cm / 8) & ~63; c0 >= 0; c0 -= 64) {
                KV32 a = LOADKV(K1H, V1H, c0 + 32);
                KV32 b = LOADKV(K1H, V1H, c0);
                sub32<false, false>(c0 + 32, Qs, 3, g1, g1 * 8.f, m, a, g, c, qa0, qa1, qb0, qb1, lA, lB, oA, oB);
                sub32<false, false>(c0,      Qs, 3, g1, g1 * 8.f, m, b, g, c, qa0, qa1, qb0, qb1, lA, lB, oA, oB);
            }
        }
    }
    // ---- level 2: 64-key iterations (<=2) ----
    {
        int cm = Qs - 160;                 // (Qs+31)-128-63
        if (cm >= 0) {
            for (int c0 = ((cm / 64) & ~63); c0 >= 0; c0 -= 64) {
                KV32 a = LOADKV(K2H, V2H, c0 + 32);
                KV32 b = LOADKV(K2H, V2H, c0);
                sub32<false, false>(c0 + 32, Qs, 6, g2, g2 * 64.f, m, a, g, c, qa0, qa1, qb0, qb1, lA, lB, oA, oB);
                sub32<false, false>(c0,      Qs, 6, g2, g2 * 64.f, m, b, g, c, qa0, qa1, qb0, qb1, lA, lB, oA, oB);
            }
        }
    }
    // ---- level 3: single 32-chunk group (16 real, padded; mask guards the pad) ----
    {
        int cm = Qs - 608;                 // (Qs+31)-128-511
        if (cm >= 0) {
            KV32 t = LOADKV(K3H, V3H, 0);
            sub32<false, false>(0, Qs, 9, g3, g3 * 512.f, m, t, g, c, qa0, qa1, qb0, qb1, lA, lB, oA, oB);
        }
    }

    // final l reduce over the 4 g-lanes of each query column
    float ltA = lA + __shfl_xor(lA, 16); ltA += __shfl_xor(ltA, 32);
    float ltB = lB + __shfl_xor(lB, 16); ltB += __shfl_xor(ltB, 32);
    float invA = 1.0f / fmaxf(ltA, 1e-8f);
    float invB = 1.0f / fmaxf(ltB, 1e-8f);

    float* orowA = out + ((size_t)(h * NTOK + Qs + c)) * DD;
    float* orowB = orowA + 16 * DD;
#pragma unroll
    for (int db = 0; db < 4; ++db) {
        float4 x;
        x.x = oA[db][0] * invA; x.y = oA[db][1] * invA;
        x.z = oA[db][2] * invA; x.w = oA[db][3] * invA;
        *(float4*)(orowA + db * 16 + 4 * g) = x;
        float4 y;
        y.x = oB[db][0] * invB; y.y = oB[db][1] * invB;
        y.z = oB[db][2] * invB; y.w = oB[db][3] * invB;
        *(float4*)(orowB + db * 16 + 4 * g) = y;
    }
}

extern "C" void kernel_launch(void* const* d_in, const int* in_sizes, int n_in,
                              void* d_out, int out_size, void* d_ws, size_t ws_size,
                              hipStream_t stream) {
    const float* q = (const float*)d_in[0];
    const float* k = (const float*)d_in[1];
    const float* v = (const float*)d_in[2];
    const float* gam = (const float*)d_in[3];
    float* out = (float*)d_out;

    char* w = (char*)d_ws;
    const size_t bigN = (size_t)NH * NTOK * DD * sizeof(unsigned short);
    unsigned short* Kbuf = (unsigned short*)w;  w += bigN;
    unsigned short* Vtb  = (unsigned short*)w;  w += bigN;                       // blocked
    unsigned short* K1   = (unsigned short*)w;  w += (size_t)NH * 1024 * DD * 2;
    unsigned short* Vt1  = (unsigned short*)w;  w += (size_t)NH * 1024 * DD * 2; // blocked
    unsigned short* K2   = (unsigned short*)w;  w += (size_t)NH * 128 * DD * 2;
    unsigned short* Vt2  = (unsigned short*)w;  w += (size_t)NH * 128 * DD * 2;  // blocked
    unsigned short* K3   = (unsigned short*)w;  w += (size_t)NH * 32 * DD * 2;
    unsigned short* Vt3  = (unsigned short*)w;  w += (size_t)NH * 32 * DD * 2;   // blocked

    prep_kv<<<NH * (NTOK / 64), 256, 0, stream>>>(k, v, Kbuf, Vtb);
    pool1_b<<<NH * 1024 * DD / 256, 256, 0, stream>>>(Kbuf, Vtb, K1, Vt1);
    pool2_b<<<NH * 128 * DD / 256, 256, 0, stream>>>(K1, Vt1, K2, Vt2);
    pool3_b<<<NH * 32 * DD / 256, 256, 0, stream>>>(K2, Vt2, K3, Vt3);

    attn_mfma<<<NH * 64, 256, 0, stream>>>(q, Kbuf, Vtb, K1, Vt1, K2, Vt2, K3, Vt3, gam, out);
}